// Round 5
// baseline (260.854 us; speedup 1.0000x reference)
//
#include <hip/hip_runtime.h>
#include <hip/hip_bf16.h>
#include <stdint.h>

// ---- problem dims (fixed) ----
#define B_   8
#define S_   2048
#define D_   768
#define BS_  16384   // B_*S_
#define F_   1536    // 2*D_
#define L2E  1.4426950408889634f

typedef __attribute__((ext_vector_type(8))) short short8;    // 8 bf16 MFMA frag
typedef __attribute__((ext_vector_type(4))) float f32x4;     // 16x16 acc frag
typedef __attribute__((ext_vector_type(16))) float f32x16;   // 32x32 acc frag
typedef __attribute__((ext_vector_type(4))) float float4v;
typedef __attribute__((ext_vector_type(2))) float float2v;
typedef __attribute__((ext_vector_type(4))) unsigned short ushort4v;

__device__ __forceinline__ unsigned short f2bf(float f) {
  union { float f; unsigned u; } v; v.f = f;
  unsigned r = v.u + 0x7FFFu + ((v.u >> 16) & 1u);   // RNE
  return (unsigned short)(r >> 16);
}
__device__ __forceinline__ float exp2_fast(float x) {
  float r; asm("v_exp_f32 %0, %1" : "=v"(r) : "v"(x)); return r;
}
__device__ __forceinline__ unsigned cvtpk_bf16(float lo, float hi) {
  unsigned r; asm("v_cvt_pk_bf16_f32 %0, %1, %2" : "=v"(r) : "v"(lo), "v"(hi)); return r;
}

#define GLOAD16(gp, lp) \
  __builtin_amdgcn_global_load_lds((const __attribute__((address_space(1))) void*)(gp), \
                                   (__attribute__((address_space(3))) void*)(lp), 16, 0, 0)

// ---------------- cast kernel (8 elem/thread) ----------------
__global__ __launch_bounds__(256) void k_cast8(const float* __restrict__ src,
                                               unsigned short* __restrict__ dst, int n) {
  int i = (blockIdx.x * 256 + threadIdx.x) * 8;
  if (i >= n) return;
  float4v a = *(const float4v*)(src + i);
  float4v b2 = *(const float4v*)(src + i + 4);
  union { short8 s; unsigned u[4]; } o;
  o.u[0] = cvtpk_bf16(a[0], a[1]); o.u[1] = cvtpk_bf16(a[2], a[3]);
  o.u[2] = cvtpk_bf16(b2[0], b2[1]); o.u[3] = cvtpk_bf16(b2[2], b2[3]);
  *(short8*)(dst + i) = o.s;
}

// src[R][C] f32 -> dst[C][R] bf16   (R,C multiples of 32)
__global__ __launch_bounds__(256) void k_transpose_cast(const float* __restrict__ src,
                                                        unsigned short* __restrict__ dst,
                                                        int R, int C) {
  __shared__ float tile[32][33];
  int bx = blockIdx.x * 32;   // C index
  int by = blockIdx.y * 32;   // R index
  int tx = threadIdx.x, ty = threadIdx.y;   // block (32,8)
#pragma unroll
  for (int k = 0; k < 32; k += 8)
    tile[ty + k][tx] = src[(size_t)(by + ty + k) * C + bx + tx];
  __syncthreads();
#pragma unroll
  for (int k = 0; k < 32; k += 8)
    dst[(size_t)(bx + ty + k) * R + by + tx] = f2bf(tile[tx][ty + k]);
}

// ---------------- GEMM: C[M][768] = [A|A2][M][K] * BT[768][K]^T ----------------
// A row stride fixed at 768 (two 768-wide sources, switch at Ksplit). BT stride K.
// BK=64 (128B rows, c^(r&7) swizzle), dbuf LDS 64KB, counted vmcnt(8), setprio.
// EPI=0: f32 out + bias.  EPI=1: transpose-epilogue -> xpT[b][d][s] bf16.
template <int EPI>
__global__ __launch_bounds__(256, 2) void k_gemm(const unsigned short* __restrict__ A,
                                                 const unsigned short* __restrict__ A2,
                                                 const unsigned short* __restrict__ BT,
                                                 int K, int Ksplit,
                                                 float* __restrict__ outF,
                                                 const float* __restrict__ bias,
                                                 unsigned short* __restrict__ outT) {
  __shared__ unsigned short smem[32768];   // A0 B0 A1 B1, each [128][64]
  int lin = blockIdx.x;                    // 768 blocks, bijective XCD chunk
  int nl  = (lin & 7) * 96 + (lin >> 3);
  int mBase = (nl / 6) * 128;
  int nBase = (nl % 6) * 128;
  int t = threadIdx.x;
  int w = t >> 6, l = t & 63;
  int lm = l & 15, lg = l >> 4;
  int wm = w >> 1, wn = w & 1;   // 2x2 waves, 64x64 per wave
  f32x4 acc[4][4] = {};
  const int KT = K >> 6;

  auto stage = [&](int kt, int half) {
    unsigned short* Ab = smem + half * 16384;
    unsigned short* Bb = Ab + 8192;
    const unsigned short* As = (kt < Ksplit) ? A : A2;
    int ka = (kt < Ksplit) ? kt : kt - Ksplit;
#pragma unroll
    for (int i = 0; i < 4; ++i) {
      int g = i * 256 + t;
      int r = g >> 3;
      int c = (g & 7) ^ (r & 7);           // pre-swizzled source chunk
      GLOAD16(As + (size_t)(mBase + r) * 768 + ka + c * 8, (char*)Ab + i * 4096 + w * 1024);
      GLOAD16(BT + (size_t)(nBase + r) * K + kt + c * 8, (char*)Bb + i * 4096 + w * 1024);
    }
  };

  stage(0, 0);
  for (int kt = 0; kt < KT; ++kt) {
    int half = kt & 1;
    if (kt + 1 < KT) {
      stage((kt + 1) * 64, half ^ 1);
      asm volatile("s_waitcnt vmcnt(8)" ::: "memory");
    } else {
      asm volatile("s_waitcnt vmcnt(0)" ::: "memory");
    }
    __builtin_amdgcn_s_barrier();
    __builtin_amdgcn_sched_barrier(0);
    unsigned short* Ab = smem + half * 16384;
    unsigned short* Bb = Ab + 8192;
    __builtin_amdgcn_s_setprio(1);
#pragma unroll
    for (int ks = 0; ks < 2; ++ks) {
      short8 af[4], bfr[4];
#pragma unroll
      for (int mi = 0; mi < 4; ++mi) {
        int r = wm * 64 + mi * 16 + lm;
        int c = (ks * 4 + lg) ^ (r & 7);
        af[mi] = *(const short8*)(Ab + r * 64 + c * 8);
      }
#pragma unroll
      for (int ni = 0; ni < 4; ++ni) {
        int r = wn * 64 + ni * 16 + lm;
        int c = (ks * 4 + lg) ^ (r & 7);
        bfr[ni] = *(const short8*)(Bb + r * 64 + c * 8);
      }
#pragma unroll
      for (int mi = 0; mi < 4; ++mi)
#pragma unroll
        for (int ni = 0; ni < 4; ++ni)
          acc[mi][ni] = __builtin_amdgcn_mfma_f32_16x16x32_bf16(af[mi], bfr[ni], acc[mi][ni], 0, 0, 0);
    }
    __builtin_amdgcn_s_setprio(0);
    __builtin_amdgcn_sched_barrier(0);
    __builtin_amdgcn_s_barrier();
  }

  if (EPI == 0) {
#pragma unroll
    for (int mi = 0; mi < 4; ++mi) {
      int m = mBase + wm * 64 + mi * 16 + lg * 4;
#pragma unroll
      for (int ni = 0; ni < 4; ++ni) {
        int n = nBase + wn * 64 + ni * 16 + lm;
        float bv = bias[n];
#pragma unroll
        for (int r = 0; r < 4; ++r)
          outF[(size_t)(m + r) * 768 + n] = acc[mi][ni][r] + bv;
      }
    }
  } else {
    // write acc into smem as [n][m] bf16, then store xpT rows coalesced
#pragma unroll
    for (int mi = 0; mi < 4; ++mi) {
#pragma unroll
      for (int ni = 0; ni < 4; ++ni) {
        int nl2 = wn * 64 + ni * 16 + lm;
        int ml = wm * 64 + mi * 16 + lg * 4;
        ushort4v o;
        o[0] = f2bf(acc[mi][ni][0]); o[1] = f2bf(acc[mi][ni][1]);
        o[2] = f2bf(acc[mi][ni][2]); o[3] = f2bf(acc[mi][ni][3]);
        *(ushort4v*)(&smem[nl2 * 128 + ml]) = o;
      }
    }
    __syncthreads();
    int b = mBase >> 11;
    int sBase = mBase & 2047;
#pragma unroll
    for (int it = 0; it < 8; ++it) {
      int nRow = it * 16 + (t >> 4);
      int m0 = (t & 15) * 8;
      short8 v = *(const short8*)(&smem[nRow * 128 + m0]);
      *(short8*)(outT + ((size_t)b * D_ + nBase + nRow) * S_ + sBase + m0) = v;
    }
  }
}

// ---------------- alphas ----------------
__global__ __launch_bounds__(256) void k_alphas(const unsigned short* __restrict__ xpT,
                                                const float* __restrict__ a_src,
                                                const float* __restrict__ a_dst,
                                                float* __restrict__ as, float* __restrict__ ad) {
  __shared__ float rs[4][64], rd[4][64];
  int b = blockIdx.y;
  int sl = threadIdx.x & 63, part = threadIdx.x >> 6;
  int s = blockIdx.x * 64 + sl;
  const unsigned short* p = xpT + (size_t)b * D_ * S_ + s;
  float accs = 0.f, accd = 0.f;
  for (int d = part * 192; d < part * 192 + 192; ++d) {
    union { unsigned u; float f; } v; v.u = ((unsigned)p[(size_t)d * S_]) << 16;
    accs = fmaf(a_src[d], v.f, accs);
    accd = fmaf(a_dst[d], v.f, accd);
  }
  rs[part][sl] = accs; rd[part][sl] = accd;
  __syncthreads();
  if (threadIdx.x < 64) {
    int tt = threadIdx.x;
    as[b * S_ + blockIdx.x * 64 + tt] = rs[0][tt] + rs[1][tt] + rs[2][tt] + rs[3][tt];
    ad[b * S_ + blockIdx.x * 64 + tt] = rd[0][tt] + rd[1][tt] + rd[2][tt] + rd[3][tt];
  }
}

// per-batch max of alpha_src
__global__ __launch_bounds__(256) void k_bmax(const float* __restrict__ as, float* __restrict__ Ms) {
  __shared__ float red[256];
  int b = blockIdx.x, t = threadIdx.x;
  float m = -1e30f;
#pragma unroll
  for (int k = 0; k < 8; ++k) m = fmaxf(m, as[b * S_ + t + k * 256]);
  red[t] = m;
  __syncthreads();
  for (int st = 128; st > 0; st >>= 1) {
    if (t < st) red[t] = fmaxf(red[t], red[t + st]);
    __syncthreads();
  }
  if (t == 0) Ms[b] = red[0];
}

// stats: ccAB[i] = ((d_i-m_i)L2E - log2 l_i, (0.2 d_i-m_i)L2E - log2 l_i) pairs
//        sjAB[j] = (s_j*L2E, 0.2*s_j*L2E) pairs
__global__ __launch_bounds__(256) void k_stats(const float* __restrict__ as,
                                               const float* __restrict__ ad,
                                               const float* __restrict__ Ms,
                                               float* __restrict__ ccAB,
                                               float* __restrict__ sjAB) {
  __shared__ float sjl[S_];
  __shared__ float red[4][64];
  int b = blockIdx.y;
  int t = threadIdx.x;
#pragma unroll
  for (int k = 0; k < 8; ++k) sjl[t + k * 256] = as[b * S_ + t + k * 256];
  __syncthreads();
  int ilc = t & 63, part = t >> 6;
  int i = blockIdx.x * 64 + ilc;
  float di = ad[b * S_ + i];
  float xm = di + Ms[b];
  float mi = fmaxf(xm, 0.2f * xm);
  float lsum = 0.f;
  for (int j = part * 512; j < part * 512 + 512; ++j) {
    float x = di + sjl[j];
    float z = fmaxf(x, 0.2f * x);
    lsum += __expf(z - mi);
  }
  red[part][ilc] = lsum;
  __syncthreads();
  if (t < 64) {
    int ig = blockIdx.x * 64 + t;      // part==0 -> own di, mi valid
    float lt = red[0][t] + red[1][t] + red[2][t] + red[3][t];
    float lg2 = __log2f(lt);
    ccAB[(b * S_ + ig) * 2 + 0] = (di - mi) * L2E - lg2;
    ccAB[(b * S_ + ig) * 2 + 1] = fmaf(0.2f, di, -mi) * L2E - lg2;
    sjAB[(b * S_ + ig) * 2 + 0] = sjl[ig] * L2E;
    sjAB[(b * S_ + ig) * 2 + 1] = 0.2f * sjl[ig] * L2E;
  }
}

// ---------------- aggregation v6: P in registers, X in LDS ----------------
// 256 thr, 4 waves 2m x 2n; wave 64i x 96d (M2 x N3 of 32x32x16); block 128i x 192d.
// BK=32, X dbuf (c^(r&3) swizzle, bank-free), P generated per-lane into A-frags.
// Pipeline: read frags -> B1 -> stage(tt+2 into freed buf) -> MFMA -> vmcnt(3) -> B2.
__global__ __launch_bounds__(256, 2) void k_agg(const unsigned short* __restrict__ xpT,
                                                const float* __restrict__ ccAB,
                                                const float* __restrict__ sjABg,
                                                const float* __restrict__ b_gat,
                                                unsigned short* __restrict__ gout) {
  __shared__ unsigned short X0[192 * 32], X1[192 * 32];   // 12KB each
  __shared__ float sAB[2 * S_];                            // 16KB (A_j,B_j pairs)

  int bid = blockIdx.x;          // 512 blocks; bid&7 = batch -> per-XCD L2 locality
  int b = bid & 7;
  int within = bid >> 3;         // 0..63
  int mB = (within & 15) * 128;
  int dB = (within >> 4) * 192;

  int t = threadIdx.x;
  int w = t >> 6, l = t & 63;
  int lr = l & 31, lh = l >> 5;
  int wm = w >> 1, wn = w & 1;   // wave: i [wm*64,+64), d [wn*96,+96)

  const unsigned short* Xsrc = xpT + ((size_t)b * D_ + dB) * S_;

  // --- prologue loads (order matters for vmcnt counting) ---
  int i0 = mB + wm * 64 + lr;
  float2v c0 = *(const float2v*)(ccAB + (size_t)(b * S_ + i0) * 2);        // vm 1
  float2v c1 = *(const float2v*)(ccAB + (size_t)(b * S_ + i0 + 32) * 2);   // vm 2
#pragma unroll
  for (int it = 0; it < 4; ++it)                                           // vm 3..6
    GLOAD16(sjABg + (size_t)b * S_ * 2 + (it * 256 + t) * 4, (char*)sAB + (it * 256 + t) * 16);

  auto stage = [&](int jt, char* Xb) {
#pragma unroll
    for (int is = 0; is < 3; ++is) {
      int g = is * 256 + t;            // 768 slots = 192 rows x 4 chunks(16B)
      int r = g >> 2, p = g & 3;
      int c = p ^ (r & 3);             // logical j-chunk for this physical slot
      GLOAD16(Xsrc + (size_t)r * S_ + jt + c * 8, Xb + g * 16);
    }
  };
  stage(0, (char*)X0);                                                     // vm 7..9
  stage(32, (char*)X1);                                                    // vm 10..12
  asm volatile("s_waitcnt vmcnt(3)" ::: "memory");   // ccAB+sAB+X0 landed; X1 in flight
  float Ap0 = c0[0], Bp0 = c0[1], Ap1 = c1[0], Bp1 = c1[1];
  __builtin_amdgcn_s_barrier();

  // P-fragment generator: rows (lane-local), j in [jb, jb+8)
  auto genfrag = [&](int jb, float Ap, float Bp) -> short8 {
    const float* sp = sAB + 2 * jb;
    float4v s0 = *(const float4v*)(sp);
    float4v s1 = *(const float4v*)(sp + 4);
    float4v s2 = *(const float4v*)(sp + 8);
    float4v s3 = *(const float4v*)(sp + 12);
    float p0 = exp2_fast(fmaxf(Ap + s0[0], Bp + s0[1]));
    float p1 = exp2_fast(fmaxf(Ap + s0[2], Bp + s0[3]));
    float p2 = exp2_fast(fmaxf(Ap + s1[0], Bp + s1[1]));
    float p3 = exp2_fast(fmaxf(Ap + s1[2], Bp + s1[3]));
    float p4 = exp2_fast(fmaxf(Ap + s2[0], Bp + s2[1]));
    float p5 = exp2_fast(fmaxf(Ap + s2[2], Bp + s2[3]));
    float p6 = exp2_fast(fmaxf(Ap + s3[0], Bp + s3[1]));
    float p7 = exp2_fast(fmaxf(Ap + s3[2], Bp + s3[3]));
    union { short8 s; unsigned u[4]; } pk;
    pk.u[0] = cvtpk_bf16(p0, p1); pk.u[1] = cvtpk_bf16(p2, p3);
    pk.u[2] = cvtpk_bf16(p4, p5); pk.u[3] = cvtpk_bf16(p6, p7);
    return pk.s;
  };

  f32x16 acc[2][3] = {};
  for (int tt = 0; tt < 64; ++tt) {
    unsigned short* Xc = (tt & 1) ? X1 : X0;
    int jt = tt * 32;
    // A-frags in registers (P on the fly); s-reads are LDS broadcasts
    short8 av[2][2];
    av[0][0] = genfrag(jt + lh * 8, Ap0, Bp0);
    av[1][0] = genfrag(jt + lh * 8, Ap1, Bp1);
    av[0][1] = genfrag(jt + 16 + lh * 8, Ap0, Bp0);
    av[1][1] = genfrag(jt + 16 + lh * 8, Ap1, Bp1);
    // B-frags from LDS (bank-conflict-free via c^(r&3))
    short8 bv[3][2];
#pragma unroll
    for (int ni = 0; ni < 3; ++ni)
#pragma unroll
      for (int ks = 0; ks < 2; ++ks) {
        int row = wn * 96 + ni * 32 + lr;
        int phys = (ks * 2 + lh) ^ (row & 3);
        bv[ni][ks] = *(const short8*)(Xc + row * 32 + phys * 8);
      }
    asm volatile("s_waitcnt lgkmcnt(0)" ::: "memory");
    __builtin_amdgcn_sched_barrier(0);
    __builtin_amdgcn_s_barrier();            // B1: all waves done reading Xc
    if (tt < 62) stage((tt + 2) * 32, (char*)Xc);
    __builtin_amdgcn_s_setprio(1);
#pragma unroll
    for (int ks = 0; ks < 2; ++ks)
#pragma unroll
      for (int mi = 0; mi < 2; ++mi)
#pragma unroll
        for (int ni = 0; ni < 3; ++ni)
          acc[mi][ni] = __builtin_amdgcn_mfma_f32_32x32x16_bf16(av[mi][ks], bv[ni][ks], acc[mi][ni], 0, 0, 0);
    __builtin_amdgcn_s_setprio(0);
    __builtin_amdgcn_sched_barrier(0);
    if (tt < 62) asm volatile("s_waitcnt vmcnt(3)" ::: "memory");  // X[tt+1] landed
    else         asm volatile("s_waitcnt vmcnt(0)" ::: "memory");
    __builtin_amdgcn_s_barrier();            // B2: X[tt+1] published
  }

  // epilogue: gout[i][d] = acc + b_gat   (1/l, m folded into P)
#pragma unroll
  for (int mi = 0; mi < 2; ++mi)
#pragma unroll
    for (int ni = 0; ni < 3; ++ni) {
      int col = dB + wn * 96 + ni * 32 + lr;
      float bg = b_gat[col];
#pragma unroll 16
      for (int reg = 0; reg < 16; ++reg) {
        int row = mB + wm * 64 + mi * 32 + (reg & 3) + 8 * (reg >> 2) + 4 * lh;
        gout[(size_t)(b * S_ + row) * D_ + col] = f2bf(acc[mi][ni][reg] + bg);
      }
    }
}

// ---------------- launch ----------------
extern "C" void kernel_launch(void* const* d_in, const int* in_sizes, int n_in,
                              void* d_out, int out_size, void* d_ws, size_t ws_size,
                              hipStream_t stream) {
  const float* hs   = (const float*)d_in[0];
  const float* to   = (const float*)d_in[1];
  const float* Wg   = (const float*)d_in[2];
  const float* asrc = (const float*)d_in[3];
  const float* adst = (const float*)d_in[4];
  const float* bg   = (const float*)d_in[5];
  const float* Wf   = (const float*)d_in[6];
  const float* bfu  = (const float*)d_in[7];
  float* out = (float*)d_out;

  char* ws = (char*)d_ws;
  size_t off = 0;
  auto alloc = [&](size_t bytes) {
    char* p = ws + off;
    off += (bytes + 255) & ~(size_t)255;
    return p;
  };
  unsigned short* hs_bf = (unsigned short*)alloc((size_t)BS_ * D_ * 2);
  unsigned short* to_bf = (unsigned short*)alloc((size_t)BS_ * D_ * 2);
  unsigned short* xpT   = (unsigned short*)alloc((size_t)B_ * D_ * S_ * 2);
  unsigned short* gout  = (unsigned short*)alloc((size_t)BS_ * D_ * 2);
  unsigned short* WgT   = (unsigned short*)alloc((size_t)D_ * D_ * 2);
  unsigned short* WfT   = (unsigned short*)alloc((size_t)D_ * F_ * 2);
  float* as   = (float*)alloc((size_t)BS_ * 4);
  float* ad   = (float*)alloc((size_t)BS_ * 4);
  float* ccAB = (float*)alloc((size_t)BS_ * 8);
  float* sjAB = (float*)alloc((size_t)BS_ * 8);
  float* Ms   = (float*)alloc(256);

  int n = BS_ * D_;
  k_cast8<<<n / 2048, 256, 0, stream>>>(hs, hs_bf, n);
  k_cast8<<<n / 2048, 256, 0, stream>>>(to, to_bf, n);
  k_transpose_cast<<<dim3(D_ / 32, D_ / 32), dim3(32, 8), 0, stream>>>(Wg, WgT, D_, D_);
  k_transpose_cast<<<dim3(D_ / 32, F_ / 32), dim3(32, 8), 0, stream>>>(Wf, WfT, F_, D_);
  k_gemm<1><<<768, 256, 0, stream>>>(hs_bf, hs_bf, WgT, D_, D_, nullptr, nullptr, xpT);
  k_alphas<<<dim3(32, B_), 256, 0, stream>>>(xpT, asrc, adst, as, ad);
  k_bmax<<<B_, 256, 0, stream>>>(as, Ms);
  k_stats<<<dim3(32, B_), 256, 0, stream>>>(as, ad, Ms, ccAB, sjAB);
  k_agg<<<512, 256, 0, stream>>>(xpT, ccAB, sjAB, bg, gout);
  k_gemm<0><<<768, 256, 0, stream>>>(to_bf, gout, WfT, F_, D_, out, bfu, nullptr);
}